// Round 1
// baseline (285.734 us; speedup 1.0000x reference)
//
#include <hip/hip_runtime.h>

#define BN 1024      // B
#define EN 50000     // E
#define CN 512       // CLASS_NUM

// ---------------------------------------------------------------------------
// Kernel 1: per-wave dot products.
//   waves [0, EN)        : parts[j]      = dot(tail[j, :], W2)
//   waves [EN, EN+BN)    : parts[EN + i] = dot(hr[i, :],  W1) + b   (b folded)
// One wave (64 lanes) per 512-float row: each lane reads 2 float4 (fully
// coalesced, 16B/lane), then a 64-lane shuffle tree reduction.
// ---------------------------------------------------------------------------
__global__ __launch_bounds__(256) void dots_kernel(
    const float* __restrict__ hr,
    const float* __restrict__ tail,
    const float* __restrict__ W,
    const float* __restrict__ bptr,
    float* __restrict__ parts)
{
    const int gtid = blockIdx.x * blockDim.x + threadIdx.x;
    const int wave = gtid >> 6;
    const int lane = threadIdx.x & 63;
    if (wave >= EN + BN) return;

    const float* row;
    const float* w;
    if (wave < EN) {
        row = tail + (size_t)wave * CN;
        w   = W + CN;            // W2 = W[0, 512:1024]
    } else {
        row = hr + (size_t)(wave - EN) * CN;
        w   = W;                 // W1 = W[0, 0:512]
    }

    const float4* r4 = (const float4*)row;
    const float4* w4 = (const float4*)w;

    float4 a0 = r4[lane];
    float4 b0 = w4[lane];
    float4 a1 = r4[lane + 64];
    float4 b1 = w4[lane + 64];

    float sum = a0.x * b0.x + a0.y * b0.y + a0.z * b0.z + a0.w * b0.w
              + a1.x * b1.x + a1.y * b1.y + a1.z * b1.z + a1.w * b1.w;

    // 64-lane butterfly reduction
    #pragma unroll
    for (int off = 32; off > 0; off >>= 1)
        sum += __shfl_down(sum, off, 64);

    if (lane == 0) {
        if (wave < EN) parts[wave] = sum;
        else           parts[wave] = sum + bptr[0];   // fold bias into hr_part
    }
}

// ---------------------------------------------------------------------------
// Kernel 2: scores[i, j] = hr_part[i] + tail_part[j]   (b already folded)
// grid = (ceil(12500/256), 1024). Each thread writes one float4 of a row.
// tail_part (200 KB) is read 1024x but stays L2/L3 resident.
// Thread (0,0,0) also writes the tuple's trailing scalar 0.
// ---------------------------------------------------------------------------
__global__ __launch_bounds__(256) void bcast_kernel(
    const float* __restrict__ parts,
    float* __restrict__ out)
{
    const int i  = blockIdx.y;
    const int j4 = blockIdx.x * blockDim.x + threadIdx.x;

    const float hv = parts[EN + i];   // wave-uniform (blockIdx-indexed) -> scalar load

    if (j4 < EN / 4) {
        float4 t = ((const float4*)parts)[j4];
        float4 o;
        o.x = t.x + hv;
        o.y = t.y + hv;
        o.z = t.z + hv;
        o.w = t.w + hv;
        ((float4*)out)[(size_t)i * (EN / 4) + j4] = o;
    }

    if (i == 0 && blockIdx.x == 0 && threadIdx.x == 0) {
        out[(size_t)BN * EN] = 0.0f;   // second tuple element: literal 0
    }
}

extern "C" void kernel_launch(void* const* d_in, const int* in_sizes, int n_in,
                              void* d_out, int out_size, void* d_ws, size_t ws_size,
                              hipStream_t stream)
{
    const float* hr   = (const float*)d_in[0];   // (1024, 512)
    const float* tail = (const float*)d_in[1];   // (50000, 512)
    const float* W    = (const float*)d_in[2];   // (1, 1024)
    const float* b    = (const float*)d_in[3];   // (1,)
    float* out = (float*)d_out;
    float* parts = (float*)d_ws;                 // EN + BN floats = 204 KB

    // Kernel 1: 51024 waves, 4 waves per 256-thread block.
    const int total_waves = EN + BN;
    const int blocks1 = (total_waves + 3) / 4;
    dots_kernel<<<blocks1, 256, 0, stream>>>(hr, tail, W, b, parts);

    // Kernel 2: row-parallel broadcast add.
    dim3 grid2((EN / 4 + 255) / 256, BN);
    bcast_kernel<<<grid2, 256, 0, stream>>>(parts, out);
}

// Round 3
// 272.994 us; speedup vs baseline: 1.0467x; 1.0467x over previous
//
#include <hip/hip_runtime.h>

#define BN 1024      // B
#define EN 50000     // E
#define CN 512       // CLASS_NUM

// Native vector type (HIP's float4 is a struct; the nontemporal builtins
// require a real vector type).
typedef float v4f __attribute__((ext_vector_type(4)));

// ---------------------------------------------------------------------------
// Kernel 1: per-wave dot products.
//   waves [0, EN)     : parts[j]      = dot(tail[j, :], W2)
//   waves [EN, EN+BN) : parts[EN + i] = dot(hr[i, :],  W1) + b   (b folded)
// One wave (64 lanes) per 512-float row: each lane reads 2 v4f (fully
// coalesced, 16B/lane), then a 64-lane shuffle-tree reduction.
// tail is streamed with nontemporal loads (no reuse -> don't pollute L2).
// ---------------------------------------------------------------------------
__global__ __launch_bounds__(256) void dots_kernel(
    const float* __restrict__ hr,
    const float* __restrict__ tail,
    const float* __restrict__ W,
    const float* __restrict__ bptr,
    float* __restrict__ parts,
    float* __restrict__ out)
{
    const int gtid = blockIdx.x * blockDim.x + threadIdx.x;
    const int wave = gtid >> 6;
    const int lane = threadIdx.x & 63;
    if (wave >= EN + BN) return;

    const v4f* r4;
    const v4f* w4;
    if (wave < EN) {
        r4 = (const v4f*)(tail + (size_t)wave * CN);
        w4 = (const v4f*)(W + CN);            // W2 = W[0, 512:1024]
    } else {
        r4 = (const v4f*)(hr + (size_t)(wave - EN) * CN);
        w4 = (const v4f*)W;                   // W1 = W[0, 0:512]
    }

    v4f a0 = __builtin_nontemporal_load(&r4[lane]);
    v4f a1 = __builtin_nontemporal_load(&r4[lane + 64]);
    v4f b0 = w4[lane];        // W: tiny, reused by all waves -> cached
    v4f b1 = w4[lane + 64];

    v4f p = a0 * b0 + a1 * b1;
    float sum = p.x + p.y + p.z + p.w;

    #pragma unroll
    for (int off = 32; off > 0; off >>= 1)
        sum += __shfl_down(sum, off, 64);

    if (lane == 0) {
        if (wave < EN) parts[wave] = sum;
        else           parts[wave] = sum + bptr[0];   // fold bias into hr_part
    }
    // Trailing tuple element (scalar 0) — written here, off the hot kernel.
    if (gtid == 0) out[(size_t)BN * EN] = 0.0f;
}

// ---------------------------------------------------------------------------
// Kernel 2: scores[i, j] = hr_part[i] + tail_part[j]   (b already folded)
// grid = (25, 1024); each thread writes two v4f of a row (2048 floats /
// block). Stores are nontemporal (pure streaming); parts (200 KB) stays
// L2-resident across its 1024x reuse.
// ---------------------------------------------------------------------------
__global__ __launch_bounds__(256) void bcast_kernel(
    const float* __restrict__ parts,
    float* __restrict__ out)
{
    const int i   = blockIdx.y;
    const int j4a = blockIdx.x * 512 + threadIdx.x;        // first v4f idx
    const int j4b = j4a + 256;                             // second v4f idx

    const float hv = parts[EN + i];   // wave-uniform -> scalar load, L2-hot
    v4f* orow = (v4f*)(out + (size_t)i * EN);
    const v4f* t4 = (const v4f*)parts;

    if (j4a < EN / 4) {
        v4f o = t4[j4a] + hv;
        __builtin_nontemporal_store(o, &orow[j4a]);
    }
    if (j4b < EN / 4) {
        v4f o = t4[j4b] + hv;
        __builtin_nontemporal_store(o, &orow[j4b]);
    }
}

extern "C" void kernel_launch(void* const* d_in, const int* in_sizes, int n_in,
                              void* d_out, int out_size, void* d_ws, size_t ws_size,
                              hipStream_t stream)
{
    const float* hr   = (const float*)d_in[0];   // (1024, 512)
    const float* tail = (const float*)d_in[1];   // (50000, 512)
    const float* W    = (const float*)d_in[2];   // (1, 1024)
    const float* b    = (const float*)d_in[3];   // (1,)
    float* out = (float*)d_out;
    float* parts = (float*)d_ws;                 // EN + BN floats = 204 KB

    // Kernel 1: 51024 waves, 4 waves per 256-thread block.
    const int total_waves = EN + BN;
    const int blocks1 = (total_waves + 3) / 4;
    dots_kernel<<<blocks1, 256, 0, stream>>>(hr, tail, W, b, parts, out);

    // Kernel 2: row-parallel broadcast add, 2 v4f per thread.
    dim3 grid2((EN / 4 + 511) / 512, BN);
    bcast_kernel<<<grid2, 256, 0, stream>>>(parts, out);
}